// Round 8
// baseline (153.189 us; speedup 1.0000x reference)
//
#include <hip/hip_runtime.h>

#define B_   4
#define H_   128
#define W_   128
#define HW_  (H_*W_)     // 16384
#define CIN_ 1152
#define CP   72          // padded px stride in LDS patch (144 B)

typedef __attribute__((ext_vector_type(8))) short short8;
typedef __attribute__((ext_vector_type(4))) float floatx4;
typedef unsigned short u16;
typedef unsigned int   u32;

__device__ __forceinline__ float bf2f(u16 u){ union{u32 i; float f;} v; v.i=((u32)u)<<16; return v.f; }
__device__ __forceinline__ u16 f2bf(float f){ union{float fl; u32 i;} v; v.fl=f; u32 lsb=(v.i>>16)&1u; v.i += 0x7fffu + lsb; return (u16)(v.i>>16); }

// ---------------------------------------------------------------------------
// K1: re-layout w1 (fp32 [64][1152], col = half*576 + c*9 + ij) into bf16
//     Wt{A,B}[o][ij*64 + c]
__global__ void k_prep_w(const float* __restrict__ w1,
                         u16* __restrict__ WtA, u16* __restrict__ WtB){
    int o = blockIdx.x, sel = blockIdx.y, k = threadIdx.x;   // k in [0,576)
    int c = k & 63, ij = k >> 6;
    float v = w1[(long)o*CIN_ + sel*576 + c*9 + ij];
    u16* dst = sel ? WtB : WtA;
    dst[o*576 + ij*64 + c] = f2bf(v);
}

// ---------------------------------------------------------------------------
// K2: fp32 NCHW -> bf16 NHWC, vectorized (float4 reads, uint2 writes).
__global__ __launch_bounds__(256) void k_t_fwd(
        const float* __restrict__ nbh, const float* __restrict__ cen,
        u16* __restrict__ nbhT, u16* __restrict__ cenT){
    __shared__ u16 tile[64*68];
    int px0 = blockIdx.x * 64;
    int b   = blockIdx.y;
    const float* src = blockIdx.z ? cen : nbh;
    u16* dst         = blockIdx.z ? cenT : nbhT;
    int t  = threadIdx.x;
    int hi = t >> 4, seg = t & 15;
    #pragma unroll
    for (int p = 0; p < 4; ++p){
        int c = p*16 + hi;
        float4 v = *reinterpret_cast<const float4*>(&src[(size_t)(b*64 + c)*HW_ + px0 + seg*4]);
        u16 pk[4] = { f2bf(v.x), f2bf(v.y), f2bf(v.z), f2bf(v.w) };
        *reinterpret_cast<uint2*>(&tile[c*68 + seg*4]) = *reinterpret_cast<uint2*>(pk);
    }
    __syncthreads();
    #pragma unroll
    for (int p = 0; p < 4; ++p){
        int px = p*16 + hi;
        int cg = seg*4;
        u16 pk[4] = { tile[cg*68+px], tile[(cg+1)*68+px], tile[(cg+2)*68+px], tile[(cg+3)*68+px] };
        *reinterpret_cast<uint2*>(&dst[(size_t)(b*HW_ + px0 + px)*64 + cg]) = *reinterpret_cast<uint2*>(pk);
    }
}

// ---------------------------------------------------------------------------
// K3 v4: 3x3 conv cin=64->cout=64, zero pad, MFMA 16x16x32 bf16.
//     Block: 4 rows x 64 cols; ALL 9 weight tiles staged once; ONE barrier.
__global__ __launch_bounds__(256) void k_conv(
        const u16* __restrict__ nbhT, const u16* __restrict__ cenT,
        const u16* __restrict__ WtA, const u16* __restrict__ WtB,
        u16* __restrict__ convA, u16* __restrict__ convB){
    __shared__ __align__(16) u16 patch[6*66*CP];   // 57,024 B
    __shared__ __align__(16) u16 wall[9*64*64];    // 73,728 B
    int x0  = blockIdx.x * 64;
    int y0  = blockIdx.y * 4;
    int b   = blockIdx.z >> 1;
    int sel = blockIdx.z & 1;
    const u16* src = sel ? cenT : nbhT;
    const u16* wt  = sel ? WtB : WtA;
    u16* dst       = sel ? convB : convA;
    int tid = threadIdx.x;

    for (int q = tid; q < 9*64*8; q += 256){       // stage all 9 weight tiles
        int row = q >> 3, c8 = q & 7;              // row = ij*64 + o
        int o = row & 63, ij = row >> 6;
        *reinterpret_cast<uint4*>(&wall[row*64 + c8*8]) =
            *reinterpret_cast<const uint4*>(&wt[o*576 + ij*64 + c8*8]);
    }
    #pragma unroll
    for (int r = 0; r < 6; ++r){                   // stage 6 input rows
        int gy = y0 - 1 + r;
        bool rok = (gy >= 0) && (gy < H_);
        for (int q = tid; q < 66*8; q += 256){
            int col = q >> 3, c8 = q & 7;
            int gx = x0 - 1 + col;
            uint4 val = make_uint4(0u,0u,0u,0u);
            if (rok && gx >= 0 && gx < W_)
                val = *reinterpret_cast<const uint4*>(&src[((size_t)(b*HW_ + gy*W_ + gx))*64 + c8*8]);
            *reinterpret_cast<uint4*>(&patch[(r*66 + col)*CP + c8*8]) = val;
        }
    }
    __syncthreads();

    int lane = tid & 63;
    int m    = lane & 15;
    int qd   = lane >> 4;
    int w    = tid >> 6;          // wave = local row

    floatx4 acc[4][4] = {};
    #pragma unroll
    for (int ij = 0; ij < 9; ++ij){
        const int i = ij/3, j = ij%3;
        #pragma unroll
        for (int s = 0; s < 2; ++s){
            int c0 = s*32 + qd*8;
            short8 bv[4];
            #pragma unroll
            for (int nt = 0; nt < 4; ++nt)
                bv[nt] = *reinterpret_cast<const short8*>(&wall[(ij*64 + nt*16 + m)*64 + c0]);
            #pragma unroll
            for (int mt = 0; mt < 4; ++mt){
                short8 av = *reinterpret_cast<const short8*>(
                    &patch[((w + i)*66 + mt*16 + m + j)*CP + c0]);
                #pragma unroll
                for (int nt = 0; nt < 4; ++nt)
                    acc[mt][nt] = __builtin_amdgcn_mfma_f32_16x16x32_bf16(av, bv[nt], acc[mt][nt], 0, 0, 0);
            }
        }
    }

    // C/D layout: col(o-local) = lane&15, row(px-local) = quad*4 + reg
    size_t base = ((size_t)(b*HW_ + (y0 + w)*W_ + x0))*64;
    #pragma unroll
    for (int mt = 0; mt < 4; ++mt)
        #pragma unroll
        for (int nt = 0; nt < 4; ++nt)
            #pragma unroll
            for (int r = 0; r < 4; ++r){
                int px = mt*16 + qd*4 + r;
                int o  = nt*16 + m;
                dst[base + (size_t)px*64 + o] = f2bf(acc[mt][nt][r]);
            }
}

// ---------------------------------------------------------------------------
// att fetch: attn value k=(i-1)*3+(j-1) from lane-distributed am within the
// 16-lane group; 0 if (i,j) outside the 3x3 table (padded coords 1..3).
__device__ __forceinline__ float fetchA(float am, int lane, int i, int j){
    bool ok = (i >= 1) & (i <= 3) & (j >= 1) & (j <= 3);
    int k = (i-1)*3 + (j-1);
    k = min(max(k, 0), 8);
    float v = __shfl(am, (lane & 48) | k, 64);
    return ok ? v : 0.f;
}

// K4 v4: 16 pixels/wave, MFMA logits (r7-verified), + FUSED fp32 NCHW output
// via LDS tile (replaces k_t_bwd), phase-2 taps pair-packed -> ds_read_b128.
__global__ __launch_bounds__(256) void k_attn(
        const u16* __restrict__ nbhT,
        const u16* __restrict__ convA, const u16* __restrict__ convB,
        const float* __restrict__ mv,
        const float* __restrict__ b1, const float* __restrict__ w2,
        const float* __restrict__ b2, float* __restrict__ out){
    __shared__ __align__(16) int cwoff[64*16*2];   // 8 KB: [slot][tap] (cw,off)
    __shared__ float otile[64*66];                 // 16.9 KB: [c][px]
    int tid  = threadIdx.x;
    int lane = tid & 63;
    int w    = tid >> 6;
    int m    = lane & 15;
    int qd   = lane >> 4;
    int pix0 = blockIdx.x*64;                      // 64 px: one (b,y) half-row
    int b    = pix0 >> 14;
    int y    = (pix0 >> 7) & 127;
    int xblk = pix0 & 127;
    int x    = xblk + w*16 + m;                    // this lane's pixel
    size_t pb = (size_t)b*HW_*64;
    const u16* nb = nbhT + pb;

    // geometry (per pixel m, duplicated across qd)
    float u  = mv[(long)(b*2  )*HW_ + y*W_ + x] * 0.5f;
    float v  = mv[(long)(b*2+1)*HW_ + y*W_ + x] * 0.5f;
    float gx = fminf(fmaxf(-1.0f + x*(2.0f/127.0f) + u, -1.f), 1.f);
    float gy = fminf(fmaxf(-1.0f + y*(2.0f/127.0f) + v, -1.f), 1.f);
    float sx = (gx + 1.f) * 63.5f;
    float sy = (gy + 1.f) * 63.5f;
    float x0f = floorf(sx), y0f = floorf(sy);
    float wx = sx - x0f,    wy = sy - y0f;
    int x0i = min(max((int)x0f, 0), W_-1);
    int y0i = min(max((int)y0f, 0), H_-1);
    int x1i = min(x0i+1, W_-1);
    int y1i = min(y0i+1, H_-1);
    float wx0 = 1.f - wx, wy0 = 1.f - wy;

    // h1 A-fragments: channels c0 = s*32 + qd*8, pixel = m
    short8 av[2];
    #pragma unroll
    for (int s = 0; s < 2; ++s){
        int c0 = s*32 + qd*8;
        short8 q00 = *reinterpret_cast<const short8*>(&convA[pb + (size_t)(y0i*W_+x0i)*64 + c0]);
        short8 q01 = *reinterpret_cast<const short8*>(&convA[pb + (size_t)(y0i*W_+x1i)*64 + c0]);
        short8 q10 = *reinterpret_cast<const short8*>(&convA[pb + (size_t)(y1i*W_+x0i)*64 + c0]);
        short8 q11 = *reinterpret_cast<const short8*>(&convA[pb + (size_t)(y1i*W_+x1i)*64 + c0]);
        short8 qc  = *reinterpret_cast<const short8*>(&convB[pb + (size_t)(y*W_+x)*64 + c0]);
        short8 h;
        #pragma unroll
        for (int j = 0; j < 8; ++j){
            float t = wy0*(wx0*bf2f((u16)q00[j]) + wx*bf2f((u16)q01[j]))
                    + wy *(wx0*bf2f((u16)q10[j]) + wx*bf2f((u16)q11[j]))
                    + bf2f((u16)qc[j]) + b1[c0+j];
            t = t >= 0.f ? t : 0.1f*t;           // LeakyReLU(0.1)
            h[j] = (short)f2bf(t);
        }
        av[s] = h;
    }
    // w2 B-fragments: out-col kk = m, channels c0 = s*32 + qd*8
    short8 bv[2];
    #pragma unroll
    for (int s = 0; s < 2; ++s){
        int c0 = s*32 + qd*8;
        short8 t = {0,0,0,0,0,0,0,0};
        if (m < 9){
            #pragma unroll
            for (int j = 0; j < 8; ++j) t[j] = (short)f2bf(w2[m*64 + c0 + j]);
        }
        bv[s] = t;
    }
    floatx4 C = {0.f,0.f,0.f,0.f};
    C = __builtin_amdgcn_mfma_f32_16x16x32_bf16(av[0], bv[0], C, 0, 0, 0);
    C = __builtin_amdgcn_mfma_f32_16x16x32_bf16(av[1], bv[1], C, 0, 0, 0);
    // C layout: col = kk = lane&15, row = pixel-local = qd*4 + r

    float b2k = (m < 9) ? b2[m] : 0.f;
    float am[4];
    #pragma unroll
    for (int r = 0; r < 4; ++r){
        float e  = C[r] + b2k;
        float mx = (m < 9) ? e : -3.0e38f;
        #pragma unroll
        for (int d = 1; d < 16; d <<= 1) mx = fmaxf(mx, __shfl_xor(mx, d, 64));
        float a = (m < 9) ? __expf(e - mx) : 0.f;
        float s = a;
        #pragma unroll
        for (int d = 1; d < 16; d <<= 1) s += __shfl_xor(s, d, 64);
        am[r] = a / (9.f * s);                   // attn/9 (mean folded in)
    }

    // cw + offset per (pixel p = qd*4+r, tap t = m)
    int gpack = x0i | (y0i << 8) | ((y1i > y0i) ? 0x10000 : 0) | ((x1i > x0i) ? 0x20000 : 0);
    int at = m >> 2, bt = m & 3;
    #pragma unroll
    for (int r = 0; r < 4; ++r){
        int p   = qd*4 + r;
        int src = (lane & 48) | p;
        float wxp = __shfl(wx, src, 64);
        float wyp = __shfl(wy, src, 64);
        int   gp  = __shfl(gpack, src, 64);
        int x0p = gp & 255, y0p = (gp >> 8) & 255;
        int dy1 = (gp >> 16) & 1, dx1 = (gp >> 17) & 1;
        float wx0p = 1.f - wxp, wy0p = 1.f - wyp;
        int ia = dy1 ? at : at+1;
        int jb = dx1 ? bt : bt+1;
        float cw = wy0p*wx0p*fetchA(am[r], lane, at+1, bt+1)
                 + wy0p*wxp *fetchA(am[r], lane, at+1, jb)
                 + wyp *wx0p*fetchA(am[r], lane, ia,   bt+1)
                 + wyp *wxp *fetchA(am[r], lane, ia,   jb);
        int ry = y0p - 1 + at, rx = x0p - 1 + bt;
        bool ok = (ry >= 0) & (ry < H_) & (rx >= 0) & (rx < W_);
        int2 pr;
        pr.x = __float_as_int(ok ? cw : 0.f);
        pr.y = ok ? (ry*W_ + rx)*64 : 0;
        *reinterpret_cast<int2*>(&cwoff[((w*16 + p)*16 + m)*2]) = pr;
    }

    // phase 2: wave's own 16 slots; lane = channel; b128 pair-packed taps
    for (int s = 0; s < 16; ++s){
        int slot = w*16 + s;
        const int4* pr4 = reinterpret_cast<const int4*>(&cwoff[slot*32]);
        float acc = 0.f;
        #pragma unroll
        for (int k = 0; k < 8; ++k){
            int4 p = pr4[k];                     // wave-uniform -> broadcast
            acc += __int_as_float(p.x) * bf2f(nb[(size_t)p.y + lane]);
            acc += __int_as_float(p.z) * bf2f(nb[(size_t)p.w + lane]);
        }
        otile[lane*66 + slot] = acc;             // [c][px], 2-way bank (free)
    }
    __syncthreads();

    // fused NCHW fp32 output: c from wave, px from lane -> 256 B stores
    int px = tid & 63;
    #pragma unroll
    for (int p = 0; p < 16; ++p){
        int c = w*16 + p;
        out[(size_t)(b*64 + c)*HW_ + y*W_ + xblk + px] = otile[c*66 + px];
    }
}

// ---------------------------------------------------------------------------
extern "C" void kernel_launch(void* const* d_in, const int* in_sizes, int n_in,
                              void* d_out, int out_size, void* d_ws, size_t ws_size,
                              hipStream_t stream){
    const float* nbh = (const float*)d_in[0];
    const float* cen = (const float*)d_in[1];
    const float* mv  = (const float*)d_in[2];
    const float* w1  = (const float*)d_in[3];
    const float* b1  = (const float*)d_in[4];
    const float* w2  = (const float*)d_in[5];
    const float* b2  = (const float*)d_in[6];
    float* out = (float*)d_out;

    const size_t IMG = (size_t)B_*HW_*64;    // 4,194,304 elements
    char* ws = (char*)d_ws;
    u16* WtA   = (u16*)ws;                   // 73728 B
    u16* WtB   = WtA + 64*576;               // ends 147456
    u16* convA = (u16*)(ws + 147456);
    u16* convB = convA + IMG;
    u16* nbhT  = convB + IMG;
    u16* cenT  = nbhT  + IMG;

    hipLaunchKernelGGL(k_prep_w, dim3(64,2),    dim3(576), 0, stream, w1, WtA, WtB);
    hipLaunchKernelGGL(k_t_fwd,  dim3(256,4,2), dim3(256), 0, stream, nbh, cen, nbhT, cenT);
    hipLaunchKernelGGL(k_conv,   dim3(2,32,8),  dim3(256), 0, stream,
                       nbhT, cenT, WtA, WtB, convA, convB);
    hipLaunchKernelGGL(k_attn,   dim3(1024),    dim3(256), 0, stream,
                       nbhT, convA, convB, mv, b1, w2, b2, out);
}

// Round 9
// 144.450 us; speedup vs baseline: 1.0605x; 1.0605x over previous
//
#include <hip/hip_runtime.h>

#define B_   4
#define H_   128
#define W_   128
#define HW_  (H_*W_)     // 16384
#define CIN_ 1152

typedef __attribute__((ext_vector_type(8))) short short8;
typedef __attribute__((ext_vector_type(4))) float floatx4;
typedef unsigned short u16;
typedef unsigned int   u32;

__device__ __forceinline__ float bf2f(u16 u){ union{u32 i; float f;} v; v.i=((u32)u)<<16; return v.f; }
__device__ __forceinline__ u16 f2bf(float f){ union{float fl; u32 i;} v; v.fl=f; u32 lsb=(v.i>>16)&1u; v.i += 0x7fffu + lsb; return (u16)(v.i>>16); }

// ---------------------------------------------------------------------------
// K1: re-layout w1 (fp32 [64][1152], col = half*576 + c*9 + ij) into bf16
//     Wt{A,B}[o][ij*64 + c]
__global__ void k_prep_w(const float* __restrict__ w1,
                         u16* __restrict__ WtA, u16* __restrict__ WtB){
    int o = blockIdx.x, sel = blockIdx.y, k = threadIdx.x;   // k in [0,576)
    int c = k & 63, ij = k >> 6;
    float v = w1[(long)o*CIN_ + sel*576 + c*9 + ij];
    u16* dst = sel ? WtB : WtA;
    dst[o*576 + ij*64 + c] = f2bf(v);
}

// ---------------------------------------------------------------------------
// K2: fp32 NCHW -> bf16 NHWC, vectorized (float4 reads, uint2 writes).
__global__ __launch_bounds__(256) void k_t_fwd(
        const float* __restrict__ nbh, const float* __restrict__ cen,
        u16* __restrict__ nbhT, u16* __restrict__ cenT){
    __shared__ u16 tile[64*68];
    int px0 = blockIdx.x * 64;
    int b   = blockIdx.y;
    const float* src = blockIdx.z ? cen : nbh;
    u16* dst         = blockIdx.z ? cenT : nbhT;
    int t  = threadIdx.x;
    int hi = t >> 4, seg = t & 15;
    #pragma unroll
    for (int p = 0; p < 4; ++p){
        int c = p*16 + hi;
        float4 v = *reinterpret_cast<const float4*>(&src[(size_t)(b*64 + c)*HW_ + px0 + seg*4]);
        u16 pk[4] = { f2bf(v.x), f2bf(v.y), f2bf(v.z), f2bf(v.w) };
        *reinterpret_cast<uint2*>(&tile[c*68 + seg*4]) = *reinterpret_cast<uint2*>(pk);
    }
    __syncthreads();
    #pragma unroll
    for (int p = 0; p < 4; ++p){
        int px = p*16 + hi;
        int cg = seg*4;
        u16 pk[4] = { tile[cg*68+px], tile[(cg+1)*68+px], tile[(cg+2)*68+px], tile[(cg+3)*68+px] };
        *reinterpret_cast<uint2*>(&dst[(size_t)(b*HW_ + px0 + px)*64 + cg]) = *reinterpret_cast<uint2*>(pk);
    }
}

// ---------------------------------------------------------------------------
// K3 v6: 3x3 conv cin=64->cout=64, zero pad, MFMA 16x16x32 bf16.
//     A-operand read DIRECTLY from global NHWC (no patch LDS).
//     Weights: double-buffered per-ij wtile, stride 72 (16B-aligned,
//     2-way-bank-free bv reads). LDS = 36.9 KB -> 4 blocks/CU.
__global__ __launch_bounds__(256) void k_conv(
        const u16* __restrict__ nbhT, const u16* __restrict__ cenT,
        const u16* __restrict__ WtA, const u16* __restrict__ WtB,
        u16* __restrict__ convA, u16* __restrict__ convB){
    __shared__ __align__(16) u16 wtile[2][64*72];   // 2 x 18,432 B
    int x0  = blockIdx.x * 64;
    int y0  = blockIdx.y * 4;
    int b   = blockIdx.z >> 1;
    int sel = blockIdx.z & 1;
    const u16* src = sel ? cenT : nbhT;
    const u16* wt  = sel ? WtB : WtA;
    u16* dst       = sel ? convB : convA;
    int tid  = threadIdx.x;
    int lane = tid & 63, m = lane & 15, qd = lane >> 4, w = tid >> 6;
    int gy   = y0 + w;                              // wave's output row

    // stage ij=0 weight tile into buf 0
    for (int q = tid; q < 64*8; q += 256){
        int o = q >> 3, c8 = q & 7;
        *reinterpret_cast<uint4*>(&wtile[0][o*72 + c8*8]) =
            *reinterpret_cast<const uint4*>(&wt[o*576 + c8*8]);
    }

    const size_t rowstride = (size_t)W_*64;
    const u16* img = src + (size_t)b*HW_*64;
    floatx4 acc[4][4] = {};

    #pragma unroll
    for (int ij = 0; ij < 9; ++ij){
        __syncthreads();                            // buf[ij&1] ready; buf[(ij+1)&1] free
        if (ij < 8){
            int nij = ij + 1;
            for (int q = tid; q < 64*8; q += 256){
                int o = q >> 3, c8 = q & 7;
                *reinterpret_cast<uint4*>(&wtile[nij & 1][o*72 + c8*8]) =
                    *reinterpret_cast<const uint4*>(&wt[o*576 + nij*64 + c8*8]);
            }
        }
        const int i = ij/3, j = ij%3;
        int ry = gy + i - 1;
        if (ry >= 0 && ry < H_){                    // wave-uniform
            const u16* srow = img + (size_t)ry*rowstride;
            #pragma unroll
            for (int s = 0; s < 2; ++s){
                int c0 = s*32 + qd*8;
                short8 bv[4];
                #pragma unroll
                for (int nt = 0; nt < 4; ++nt)
                    bv[nt] = *reinterpret_cast<const short8*>(&wtile[ij & 1][(nt*16 + m)*72 + c0]);
                #pragma unroll
                for (int mt = 0; mt < 4; ++mt){
                    int gx = x0 - 1 + mt*16 + m + j;
                    short8 av = {0,0,0,0,0,0,0,0};
                    if (gx >= 0 && gx < W_)
                        av = *reinterpret_cast<const short8*>(&srow[(size_t)gx*64 + c0]);
                    #pragma unroll
                    for (int nt = 0; nt < 4; ++nt)
                        acc[mt][nt] = __builtin_amdgcn_mfma_f32_16x16x32_bf16(av, bv[nt], acc[mt][nt], 0, 0, 0);
                }
            }
        }
    }

    // C/D layout: col(o-local) = lane&15, row(px-local) = quad*4 + reg
    size_t base = ((size_t)(b*HW_ + gy*W_ + x0))*64;
    #pragma unroll
    for (int mt = 0; mt < 4; ++mt)
        #pragma unroll
        for (int nt = 0; nt < 4; ++nt)
            #pragma unroll
            for (int r = 0; r < 4; ++r){
                int px = mt*16 + qd*4 + r;
                int o  = nt*16 + m;
                dst[base + (size_t)px*64 + o] = f2bf(acc[mt][nt][r]);
            }
}

// ---------------------------------------------------------------------------
// att fetch: attn value k=(i-1)*3+(j-1) from lane-distributed am within the
// 16-lane group; 0 if (i,j) outside the 3x3 table (padded coords 1..3).
__device__ __forceinline__ float fetchA(float am, int lane, int i, int j){
    bool ok = (i >= 1) & (i <= 3) & (j >= 1) & (j <= 3);
    int k = (i-1)*3 + (j-1);
    k = min(max(k, 0), 8);
    float v = __shfl(am, (lane & 48) | k, 64);
    return ok ? v : 0.f;
}

// K4 v5: 512 threads. Waves 0-3: phase 1 (MFMA logits + cw table) for 64 px.
// ALL 8 waves: phase 2 gather, 8 slots each, 2-slot ILP. Fused NCHW output.
__global__ __launch_bounds__(512) void k_attn(
        const u16* __restrict__ nbhT,
        const u16* __restrict__ convA, const u16* __restrict__ convB,
        const float* __restrict__ mv,
        const float* __restrict__ b1, const float* __restrict__ w2,
        const float* __restrict__ b2, float* __restrict__ out){
    __shared__ __align__(16) int cwoff[64*16*2];   // 8 KB: [slot][tap] (cw,off)
    __shared__ float otile[64*66];                 // 16.9 KB: [c][px]
    int tid  = threadIdx.x;
    int lane = tid & 63;
    int w    = tid >> 6;                           // 0..7
    int m    = lane & 15;
    int qd   = lane >> 4;
    int pix0 = blockIdx.x*64;                      // 64 px: one (b,y) half-row
    int b    = pix0 >> 14;
    int y    = (pix0 >> 7) & 127;
    int xblk = pix0 & 127;
    size_t pb = (size_t)b*HW_*64;
    const u16* nb = nbhT + pb;

    if (w < 4){
        int x = xblk + w*16 + m;                   // this lane's pixel
        float u  = mv[(long)(b*2  )*HW_ + y*W_ + x] * 0.5f;
        float v  = mv[(long)(b*2+1)*HW_ + y*W_ + x] * 0.5f;
        float gx = fminf(fmaxf(-1.0f + x*(2.0f/127.0f) + u, -1.f), 1.f);
        float gy = fminf(fmaxf(-1.0f + y*(2.0f/127.0f) + v, -1.f), 1.f);
        float sx = (gx + 1.f) * 63.5f;
        float sy = (gy + 1.f) * 63.5f;
        float x0f = floorf(sx), y0f = floorf(sy);
        float wx = sx - x0f,    wy = sy - y0f;
        int x0i = min(max((int)x0f, 0), W_-1);
        int y0i = min(max((int)y0f, 0), H_-1);
        int x1i = min(x0i+1, W_-1);
        int y1i = min(y0i+1, H_-1);
        float wx0 = 1.f - wx, wy0 = 1.f - wy;

        // h1 A-fragments: channels c0 = s*32 + qd*8, pixel = m
        short8 av[2];
        #pragma unroll
        for (int s = 0; s < 2; ++s){
            int c0 = s*32 + qd*8;
            short8 q00 = *reinterpret_cast<const short8*>(&convA[pb + (size_t)(y0i*W_+x0i)*64 + c0]);
            short8 q01 = *reinterpret_cast<const short8*>(&convA[pb + (size_t)(y0i*W_+x1i)*64 + c0]);
            short8 q10 = *reinterpret_cast<const short8*>(&convA[pb + (size_t)(y1i*W_+x0i)*64 + c0]);
            short8 q11 = *reinterpret_cast<const short8*>(&convA[pb + (size_t)(y1i*W_+x1i)*64 + c0]);
            short8 qc  = *reinterpret_cast<const short8*>(&convB[pb + (size_t)(y*W_+x)*64 + c0]);
            short8 h;
            #pragma unroll
            for (int j = 0; j < 8; ++j){
                float t = wy0*(wx0*bf2f((u16)q00[j]) + wx*bf2f((u16)q01[j]))
                        + wy *(wx0*bf2f((u16)q10[j]) + wx*bf2f((u16)q11[j]))
                        + bf2f((u16)qc[j]) + b1[c0+j];
                t = t >= 0.f ? t : 0.1f*t;         // LeakyReLU(0.1)
                h[j] = (short)f2bf(t);
            }
            av[s] = h;
        }
        // w2 B-fragments: out-col kk = m, channels c0 = s*32 + qd*8
        short8 bv[2];
        #pragma unroll
        for (int s = 0; s < 2; ++s){
            int c0 = s*32 + qd*8;
            short8 t = {0,0,0,0,0,0,0,0};
            if (m < 9){
                #pragma unroll
                for (int j = 0; j < 8; ++j) t[j] = (short)f2bf(w2[m*64 + c0 + j]);
            }
            bv[s] = t;
        }
        floatx4 C = {0.f,0.f,0.f,0.f};
        C = __builtin_amdgcn_mfma_f32_16x16x32_bf16(av[0], bv[0], C, 0, 0, 0);
        C = __builtin_amdgcn_mfma_f32_16x16x32_bf16(av[1], bv[1], C, 0, 0, 0);
        // C layout: col = kk = lane&15, row = pixel-local = qd*4 + r

        float b2k = (m < 9) ? b2[m] : 0.f;
        float am[4];
        #pragma unroll
        for (int r = 0; r < 4; ++r){
            float e  = C[r] + b2k;
            float mx = (m < 9) ? e : -3.0e38f;
            #pragma unroll
            for (int d = 1; d < 16; d <<= 1) mx = fmaxf(mx, __shfl_xor(mx, d, 64));
            float a = (m < 9) ? __expf(e - mx) : 0.f;
            float s = a;
            #pragma unroll
            for (int d = 1; d < 16; d <<= 1) s += __shfl_xor(s, d, 64);
            am[r] = a / (9.f * s);                 // attn/9 (mean folded in)
        }

        // cw + offset per (pixel p = qd*4+r, tap t = m)
        int gpack = x0i | (y0i << 8) | ((y1i > y0i) ? 0x10000 : 0) | ((x1i > x0i) ? 0x20000 : 0);
        int at = m >> 2, bt = m & 3;
        #pragma unroll
        for (int r = 0; r < 4; ++r){
            int p   = qd*4 + r;
            int src = (lane & 48) | p;
            float wxp = __shfl(wx, src, 64);
            float wyp = __shfl(wy, src, 64);
            int   gp  = __shfl(gpack, src, 64);
            int x0p = gp & 255, y0p = (gp >> 8) & 255;
            int dy1 = (gp >> 16) & 1, dx1 = (gp >> 17) & 1;
            float wx0p = 1.f - wxp, wy0p = 1.f - wyp;
            int ia = dy1 ? at : at+1;
            int jb = dx1 ? bt : bt+1;
            float cw = wy0p*wx0p*fetchA(am[r], lane, at+1, bt+1)
                     + wy0p*wxp *fetchA(am[r], lane, at+1, jb)
                     + wyp *wx0p*fetchA(am[r], lane, ia,   bt+1)
                     + wyp *wxp *fetchA(am[r], lane, ia,   jb);
            int ry = y0p - 1 + at, rx = x0p - 1 + bt;
            bool ok = (ry >= 0) & (ry < H_) & (rx >= 0) & (rx < W_);
            int2 pr;
            pr.x = __float_as_int(ok ? cw : 0.f);
            pr.y = ok ? (ry*W_ + rx)*64 : 0;
            *reinterpret_cast<int2*>(&cwoff[((w*16 + p)*16 + m)*2]) = pr;
        }
    }
    __syncthreads();

    // phase 2: 8 waves x 8 slots, 2-slot ILP; lane = channel
    const u16* nbl = nb + lane;
    #pragma unroll
    for (int sp = 0; sp < 8; sp += 2){
        int slot0 = w*8 + sp;
        const int4* a4 = reinterpret_cast<const int4*>(&cwoff[slot0*32]);
        const int4* b4 = reinterpret_cast<const int4*>(&cwoff[(slot0+1)*32]);
        float acc0 = 0.f, acc1 = 0.f;
        #pragma unroll
        for (int k = 0; k < 8; ++k){
            int4 pa = a4[k];                       // wave-uniform -> broadcast
            int4 pbv = b4[k];
            acc0 += __int_as_float(pa.x)  * bf2f(nbl[(size_t)pa.y]);
            acc1 += __int_as_float(pbv.x) * bf2f(nbl[(size_t)pbv.y]);
            acc0 += __int_as_float(pa.z)  * bf2f(nbl[(size_t)pa.w]);
            acc1 += __int_as_float(pbv.z) * bf2f(nbl[(size_t)pbv.w]);
        }
        otile[lane*66 + slot0]     = acc0;         // [c][px]
        otile[lane*66 + slot0 + 1] = acc1;
    }
    __syncthreads();

    // fused NCHW fp32 output: c from wave (8 each), px from lane -> 256 B rows
    int px = lane;
    #pragma unroll
    for (int p = 0; p < 8; ++p){
        int c = w*8 + p;
        out[(size_t)(b*64 + c)*HW_ + y*W_ + xblk + px] = otile[c*66 + px];
    }
}

// ---------------------------------------------------------------------------
extern "C" void kernel_launch(void* const* d_in, const int* in_sizes, int n_in,
                              void* d_out, int out_size, void* d_ws, size_t ws_size,
                              hipStream_t stream){
    const float* nbh = (const float*)d_in[0];
    const float* cen = (const float*)d_in[1];
    const float* mv  = (const float*)d_in[2];
    const float* w1  = (const float*)d_in[3];
    const float* b1  = (const float*)d_in[4];
    const float* w2  = (const float*)d_in[5];
    const float* b2  = (const float*)d_in[6];
    float* out = (float*)d_out;

    const size_t IMG = (size_t)B_*HW_*64;    // 4,194,304 elements
    char* ws = (char*)d_ws;
    u16* WtA   = (u16*)ws;                   // 73728 B
    u16* WtB   = WtA + 64*576;               // ends 147456
    u16* convA = (u16*)(ws + 147456);
    u16* convB = convA + IMG;
    u16* nbhT  = convB + IMG;
    u16* cenT  = nbhT  + IMG;

    hipLaunchKernelGGL(k_prep_w, dim3(64,2),    dim3(576), 0, stream, w1, WtA, WtB);
    hipLaunchKernelGGL(k_t_fwd,  dim3(256,4,2), dim3(256), 0, stream, nbh, cen, nbhT, cenT);
    hipLaunchKernelGGL(k_conv,   dim3(2,32,8),  dim3(256), 0, stream,
                       nbhT, cenT, WtA, WtB, convA, convB);
    hipLaunchKernelGGL(k_attn,   dim3(1024),    dim3(512), 0, stream,
                       nbhT, convA, convB, mv, b1, w2, b2, out);
}

// Round 11
// 140.302 us; speedup vs baseline: 1.0919x; 1.0296x over previous
//
#include <hip/hip_runtime.h>

#define B_   4
#define H_   128
#define W_   128
#define HW_  (H_*W_)     // 16384
#define CIN_ 1152

typedef __attribute__((ext_vector_type(8))) short short8;
typedef __attribute__((ext_vector_type(4))) float floatx4;
typedef unsigned short u16;
typedef unsigned int   u32;

__device__ __forceinline__ float bf2f(u16 u){ union{u32 i; float f;} v; v.i=((u32)u)<<16; return v.f; }
__device__ __forceinline__ u16 f2bf(float f){ union{float fl; u32 i;} v; v.fl=f; u32 lsb=(v.i>>16)&1u; v.i += 0x7fffu + lsb; return (u16)(v.i>>16); }

// ---------------------------------------------------------------------------
// K2+K1 fused: z<2 -> fp32 NCHW -> bf16 NHWC transpose (nbh/cen);
//              z==2 -> w1 re-layout into Wt{A,B}[o][ij*64+c] + w2 -> bf16.
__global__ __launch_bounds__(256) void k_t_fwd(
        const float* __restrict__ nbh, const float* __restrict__ cen,
        const float* __restrict__ w1, const float* __restrict__ w2,
        u16* __restrict__ nbhT, u16* __restrict__ cenT,
        u16* __restrict__ WtA, u16* __restrict__ WtB, u16* __restrict__ w2bf){
    __shared__ u16 tile[64*68];
    int t = threadIdx.x;
    if (blockIdx.z == 2){
        int id = blockIdx.y*256 + blockIdx.x;
        if (id < 288){                             // w1 re-layout (73728 elems)
            int e = id*256 + t;
            int o = e / 1152;
            int r = e - o*1152;
            int sel = r / 576;
            int k = r - sel*576;
            int c = k & 63, ij = k >> 6;
            float v = w1[(long)o*CIN_ + sel*576 + c*9 + ij];
            u16* dst = sel ? WtB : WtA;
            dst[o*576 + ij*64 + c] = f2bf(v);
        } else if (id == 288){                     // w2 -> bf16 (ALL 576 elems)
            for (int e = t; e < 576; e += 256)     // r10 BUG: was `if (t < 576)`
                w2bf[e] = f2bf(w2[e]);             // with only 256 threads
        }
        return;
    }
    int px0 = blockIdx.x * 64;
    int b   = blockIdx.y;
    const float* src = blockIdx.z ? cen : nbh;
    u16* dst         = blockIdx.z ? cenT : nbhT;
    int hi = t >> 4, seg = t & 15;
    #pragma unroll
    for (int p = 0; p < 4; ++p){
        int c = p*16 + hi;
        float4 v = *reinterpret_cast<const float4*>(&src[(size_t)(b*64 + c)*HW_ + px0 + seg*4]);
        u16 pk[4] = { f2bf(v.x), f2bf(v.y), f2bf(v.z), f2bf(v.w) };
        *reinterpret_cast<uint2*>(&tile[c*68 + seg*4]) = *reinterpret_cast<uint2*>(pk);
    }
    __syncthreads();
    #pragma unroll
    for (int p = 0; p < 4; ++p){
        int px = p*16 + hi;
        int cg = seg*4;
        u16 pk[4] = { tile[cg*68+px], tile[(cg+1)*68+px], tile[(cg+2)*68+px], tile[(cg+3)*68+px] };
        *reinterpret_cast<uint2*>(&dst[(size_t)(b*HW_ + px0 + px)*64 + cg]) = *reinterpret_cast<uint2*>(pk);
    }
}

// ---------------------------------------------------------------------------
// K3 v6 (unchanged from r9): 3x3 conv, A direct from global NHWC, weights
// double-buffered per-ij wtile stride 72. LDS 36.9 KB.
__global__ __launch_bounds__(256) void k_conv(
        const u16* __restrict__ nbhT, const u16* __restrict__ cenT,
        const u16* __restrict__ WtA, const u16* __restrict__ WtB,
        u16* __restrict__ convA, u16* __restrict__ convB){
    __shared__ __align__(16) u16 wtile[2][64*72];
    int x0  = blockIdx.x * 64;
    int y0  = blockIdx.y * 4;
    int b   = blockIdx.z >> 1;
    int sel = blockIdx.z & 1;
    const u16* src = sel ? cenT : nbhT;
    const u16* wt  = sel ? WtB : WtA;
    u16* dst       = sel ? convB : convA;
    int tid  = threadIdx.x;
    int lane = tid & 63, m = lane & 15, qd = lane >> 4, w = tid >> 6;
    int gy   = y0 + w;

    for (int q = tid; q < 64*8; q += 256){
        int o = q >> 3, c8 = q & 7;
        *reinterpret_cast<uint4*>(&wtile[0][o*72 + c8*8]) =
            *reinterpret_cast<const uint4*>(&wt[o*576 + c8*8]);
    }

    const size_t rowstride = (size_t)W_*64;
    const u16* img = src + (size_t)b*HW_*64;
    floatx4 acc[4][4] = {};

    #pragma unroll
    for (int ij = 0; ij < 9; ++ij){
        __syncthreads();
        if (ij < 8){
            int nij = ij + 1;
            for (int q = tid; q < 64*8; q += 256){
                int o = q >> 3, c8 = q & 7;
                *reinterpret_cast<uint4*>(&wtile[nij & 1][o*72 + c8*8]) =
                    *reinterpret_cast<const uint4*>(&wt[o*576 + nij*64 + c8*8]);
            }
        }
        const int i = ij/3, j = ij%3;
        int ry = gy + i - 1;
        if (ry >= 0 && ry < H_){
            const u16* srow = img + (size_t)ry*rowstride;
            #pragma unroll
            for (int s = 0; s < 2; ++s){
                int c0 = s*32 + qd*8;
                short8 bv[4];
                #pragma unroll
                for (int nt = 0; nt < 4; ++nt)
                    bv[nt] = *reinterpret_cast<const short8*>(&wtile[ij & 1][(nt*16 + m)*72 + c0]);
                #pragma unroll
                for (int mt = 0; mt < 4; ++mt){
                    int gx = x0 - 1 + mt*16 + m + j;
                    short8 av = {0,0,0,0,0,0,0,0};
                    if (gx >= 0 && gx < W_)
                        av = *reinterpret_cast<const short8*>(&srow[(size_t)gx*64 + c0]);
                    #pragma unroll
                    for (int nt = 0; nt < 4; ++nt)
                        acc[mt][nt] = __builtin_amdgcn_mfma_f32_16x16x32_bf16(av, bv[nt], acc[mt][nt], 0, 0, 0);
                }
            }
        }
    }

    size_t base = ((size_t)(b*HW_ + gy*W_ + x0))*64;
    #pragma unroll
    for (int mt = 0; mt < 4; ++mt)
        #pragma unroll
        for (int nt = 0; nt < 4; ++nt)
            #pragma unroll
            for (int r = 0; r < 4; ++r){
                int px = mt*16 + qd*4 + r;
                int o  = nt*16 + m;
                dst[base + (size_t)px*64 + o] = f2bf(acc[mt][nt][r]);
            }
}

// ---------------------------------------------------------------------------
__device__ __forceinline__ float fetchA(float am, int lane, int i, int j){
    bool ok = (i >= 1) & (i <= 3) & (j >= 1) & (j <= 3);
    int k = (i-1)*3 + (j-1);
    k = min(max(k, 0), 8);
    float v = __shfl(am, (lane & 48) | k, 64);
    return ok ? v : 0.f;
}

// K4 v6: 512 threads. Waves 0-3: phase 1 (MFMA logits + cw table).
// Phase 2: 8 waves x 8 slots; DWORD-paired taps (even taps lanes 0-31, odd
// taps lanes 32-63, 2 channels per lane), cross-half shfl combine.
__global__ __launch_bounds__(512) void k_attn(
        const u16* __restrict__ nbhT,
        const u16* __restrict__ convA, const u16* __restrict__ convB,
        const float* __restrict__ mv,
        const float* __restrict__ b1, const u16* __restrict__ w2bf,
        const float* __restrict__ b2, float* __restrict__ out){
    __shared__ __align__(16) int cwoff[64*16*2];   // 8 KB: [slot][tap] (cw,off)
    __shared__ float otile[64*67];                 // 17.2 KB: [c][px] stride 67
    int tid  = threadIdx.x;
    int lane = tid & 63;
    int w    = tid >> 6;                           // 0..7
    int m    = lane & 15;
    int qd   = lane >> 4;
    int pix0 = blockIdx.x*64;                      // 64 px: one (b,y) half-row
    int b    = pix0 >> 14;
    int y    = (pix0 >> 7) & 127;
    int xblk = pix0 & 127;
    size_t pb = (size_t)b*HW_*64;
    const u16* nb = nbhT + pb;

    if (w < 4){
        int x = xblk + w*16 + m;
        float u  = mv[(long)(b*2  )*HW_ + y*W_ + x] * 0.5f;
        float v  = mv[(long)(b*2+1)*HW_ + y*W_ + x] * 0.5f;
        float gx = fminf(fmaxf(-1.0f + x*(2.0f/127.0f) + u, -1.f), 1.f);
        float gy = fminf(fmaxf(-1.0f + y*(2.0f/127.0f) + v, -1.f), 1.f);
        float sx = (gx + 1.f) * 63.5f;
        float sy = (gy + 1.f) * 63.5f;
        float x0f = floorf(sx), y0f = floorf(sy);
        float wx = sx - x0f,    wy = sy - y0f;
        int x0i = min(max((int)x0f, 0), W_-1);
        int y0i = min(max((int)y0f, 0), H_-1);
        int x1i = min(x0i+1, W_-1);
        int y1i = min(y0i+1, H_-1);
        float wx0 = 1.f - wx, wy0 = 1.f - wy;

        short8 av[2];
        #pragma unroll
        for (int s = 0; s < 2; ++s){
            int c0 = s*32 + qd*8;
            short8 q00 = *reinterpret_cast<const short8*>(&convA[pb + (size_t)(y0i*W_+x0i)*64 + c0]);
            short8 q01 = *reinterpret_cast<const short8*>(&convA[pb + (size_t)(y0i*W_+x1i)*64 + c0]);
            short8 q10 = *reinterpret_cast<const short8*>(&convA[pb + (size_t)(y1i*W_+x0i)*64 + c0]);
            short8 q11 = *reinterpret_cast<const short8*>(&convA[pb + (size_t)(y1i*W_+x1i)*64 + c0]);
            short8 qc  = *reinterpret_cast<const short8*>(&convB[pb + (size_t)(y*W_+x)*64 + c0]);
            float b1l[8];
            *reinterpret_cast<float4*>(&b1l[0]) = *reinterpret_cast<const float4*>(&b1[c0]);
            *reinterpret_cast<float4*>(&b1l[4]) = *reinterpret_cast<const float4*>(&b1[c0+4]);
            short8 h;
            #pragma unroll
            for (int j = 0; j < 8; ++j){
                float t = wy0*(wx0*bf2f((u16)q00[j]) + wx*bf2f((u16)q01[j]))
                        + wy *(wx0*bf2f((u16)q10[j]) + wx*bf2f((u16)q11[j]))
                        + bf2f((u16)qc[j]) + b1l[j];
                t = t >= 0.f ? t : 0.1f*t;         // LeakyReLU(0.1)
                h[j] = (short)f2bf(t);
            }
            av[s] = h;
        }
        short8 bv[2];
        #pragma unroll
        for (int s = 0; s < 2; ++s){
            short8 t = {0,0,0,0,0,0,0,0};
            if (m < 9)
                t = *reinterpret_cast<const short8*>(&w2bf[m*64 + s*32 + qd*8]);
            bv[s] = t;
        }
        floatx4 C = {0.f,0.f,0.f,0.f};
        C = __builtin_amdgcn_mfma_f32_16x16x32_bf16(av[0], bv[0], C, 0, 0, 0);
        C = __builtin_amdgcn_mfma_f32_16x16x32_bf16(av[1], bv[1], C, 0, 0, 0);
        // C layout: col = kk = lane&15, row = pixel-local = qd*4 + r

        float b2k = (m < 9) ? b2[m] : 0.f;
        float am[4];
        #pragma unroll
        for (int r = 0; r < 4; ++r){
            float e  = C[r] + b2k;
            float mx = (m < 9) ? e : -3.0e38f;
            #pragma unroll
            for (int d = 1; d < 16; d <<= 1) mx = fmaxf(mx, __shfl_xor(mx, d, 64));
            float a = (m < 9) ? __expf(e - mx) : 0.f;
            float s = a;
            #pragma unroll
            for (int d = 1; d < 16; d <<= 1) s += __shfl_xor(s, d, 64);
            am[r] = a / (9.f * s);                 // attn/9 (mean folded in)
        }

        int gpack = x0i | (y0i << 8) | ((y1i > y0i) ? 0x10000 : 0) | ((x1i > x0i) ? 0x20000 : 0);
        int at = m >> 2, bt = m & 3;
        #pragma unroll
        for (int r = 0; r < 4; ++r){
            int p   = qd*4 + r;
            int src = (lane & 48) | p;
            float wxp = __shfl(wx, src, 64);
            float wyp = __shfl(wy, src, 64);
            int   gp  = __shfl(gpack, src, 64);
            int x0p = gp & 255, y0p = (gp >> 8) & 255;
            int dy1 = (gp >> 16) & 1, dx1 = (gp >> 17) & 1;
            float wx0p = 1.f - wxp, wy0p = 1.f - wyp;
            int ia = dy1 ? at : at+1;
            int jb = dx1 ? bt : bt+1;
            float cw = wy0p*wx0p*fetchA(am[r], lane, at+1, bt+1)
                     + wy0p*wxp *fetchA(am[r], lane, at+1, jb)
                     + wyp *wx0p*fetchA(am[r], lane, ia,   bt+1)
                     + wyp *wxp *fetchA(am[r], lane, ia,   jb);
            int ry = y0p - 1 + at, rx = x0p - 1 + bt;
            bool ok = (ry >= 0) & (ry < H_) & (rx >= 0) & (rx < W_);
            int2 pr;
            pr.x = __float_as_int(ok ? cw : 0.f);
            pr.y = ok ? (ry*W_ + rx)*64 : 0;
            *reinterpret_cast<int2*>(&cwoff[((w*16 + p)*16 + m)*2]) = pr;
        }
    }
    __syncthreads();

    // phase 2: 8 waves x 8 slots, dword-paired taps.
    int half = lane >> 5;                          // 0: even taps, 1: odd taps
    int cp   = lane & 31;                          // channel pair index
    const u16* nbl = nb + 2*cp;
    const int2* ctab = reinterpret_cast<const int2*>(cwoff);
    #pragma unroll
    for (int sp = 0; sp < 8; sp += 2){
        int s0 = w*8 + sp, s1 = s0 + 1;
        const int2* t0 = ctab + s0*16;
        const int2* t1 = ctab + s1*16;
        float a0 = 0.f, a1 = 0.f, c0a = 0.f, c1a = 0.f;
        #pragma unroll
        for (int k = 0; k < 8; ++k){
            int2 p0 = t0[2*k + half];
            int2 p1 = t1[2*k + half];
            u32 v0 = *reinterpret_cast<const u32*>(&nbl[(size_t)p0.y]);
            u32 v1 = *reinterpret_cast<const u32*>(&nbl[(size_t)p1.y]);
            float cw0 = __int_as_float(p0.x), cw1 = __int_as_float(p1.x);
            a0  += cw0 * bf2f((u16)(v0 & 0xffffu));
            a1  += cw0 * bf2f((u16)(v0 >> 16));
            c0a += cw1 * bf2f((u16)(v1 & 0xffffu));
            c1a += cw1 * bf2f((u16)(v1 >> 16));
        }
        a0  += __shfl_xor(a0, 32, 64);
        a1  += __shfl_xor(a1, 32, 64);
        c0a += __shfl_xor(c0a, 32, 64);
        c1a += __shfl_xor(c1a, 32, 64);
        if (half == 0){
            int c2 = 2*cp;
            otile[c2*67 + s0]     = a0;
            otile[(c2+1)*67 + s0] = a1;
            otile[c2*67 + s1]     = c0a;
            otile[(c2+1)*67 + s1] = c1a;
        }
    }
    __syncthreads();

    // fused NCHW fp32 output: c from wave (8 each), px from lane -> 256 B rows
    int px = lane;
    #pragma unroll
    for (int p = 0; p < 8; ++p){
        int c = w*8 + p;
        out[(size_t)(b*64 + c)*HW_ + y*W_ + xblk + px] = otile[c*67 + px];
    }
}

// ---------------------------------------------------------------------------
extern "C" void kernel_launch(void* const* d_in, const int* in_sizes, int n_in,
                              void* d_out, int out_size, void* d_ws, size_t ws_size,
                              hipStream_t stream){
    const float* nbh = (const float*)d_in[0];
    const float* cen = (const float*)d_in[1];
    const float* mv  = (const float*)d_in[2];
    const float* w1  = (const float*)d_in[3];
    const float* b1  = (const float*)d_in[4];
    const float* w2  = (const float*)d_in[5];
    const float* b2  = (const float*)d_in[6];
    float* out = (float*)d_out;

    const size_t IMG = (size_t)B_*HW_*64;    // 4,194,304 elements
    char* ws = (char*)d_ws;
    u16* WtA   = (u16*)ws;                   // 73728 B
    u16* WtB   = WtA + 64*576;               // ends 147456
    u16* w2bf  = (u16*)(ws + 147456);        // 1152 B (+pad)
    u16* convA = (u16*)(ws + 151552);
    u16* convB = convA + IMG;
    u16* nbhT  = convB + IMG;
    u16* cenT  = nbhT  + IMG;

    hipLaunchKernelGGL(k_t_fwd, dim3(256,4,3), dim3(256), 0, stream,
                       nbh, cen, w1, w2, nbhT, cenT, WtA, WtB, w2bf);
    hipLaunchKernelGGL(k_conv,  dim3(2,32,8),  dim3(256), 0, stream,
                       nbhT, cenT, WtA, WtB, convA, convB);
    hipLaunchKernelGGL(k_attn,  dim3(1024),    dim3(512), 0, stream,
                       nbhT, convA, convB, mv, b1, w2bf, b2, out);
}